// Round 3
// baseline (8582.053 us; speedup 1.0000x reference)
//
#include <hip/hip_runtime.h>

typedef unsigned short u16;
typedef unsigned int   u32;

#define L_TOK   16384
#define C_DIM   192
#define HID_DIM 768

__device__ __forceinline__ float bf2f(u16 u) {
    u32 t = ((u32)u) << 16; float f; __builtin_memcpy(&f, &t, 4); return f;
}
__device__ __forceinline__ u16 f2bf(float f) {
    u32 t; __builtin_memcpy(&t, &f, 4);
    t += 0x7FFFu + ((t >> 16) & 1u);
    return (u16)(t >> 16);
}

// ---------------------------------------------------------------------------
// Kernel 1: per-window fused LN1 + qkv + biased/masked softmax + P@V + proj +
// residual -> x1 (f32, token order, stored in d_out).
// grid 2048, block 256. LDS 50432 B -> 3 blocks/CU. d_ws unused.
// ---------------------------------------------------------------------------
__global__ __launch_bounds__(256) void k_attnproj(
    const float* __restrict__ x, const float* __restrict__ g1v, const float* __restrict__ b1v,
    const float* __restrict__ qkvw, const float* __restrict__ qkvb,
    const float* __restrict__ relb, const float* __restrict__ projw, const float* __restrict__ projb,
    float* __restrict__ x1)
{
    __shared__ __align__(16) char smem[50432];
    u16*   xw = (u16*)smem;               // [64][196] LN1'd tokens (bf16-compressed)
    float* qs = (float*)(smem + 25088);   // [64][33]
    float* ks = qs + 64 * 33;
    float* vs = ks + 64 * 33;

    const int wi = blockIdx.x;
    const int b  = wi >> 8;
    const int hb = (wi >> 4) & 15;
    const int wb = wi & 15;
    const int t  = threadIdx.x;
    const int n  = t >> 2;        // token in window
    const int q4 = t & 3;         // quartet lane
    const int r  = n >> 3, c = n & 7;
    const int ho = (hb * 8 + r + 4) & 127;    // undo roll(-4,-4)
    const int wo = (wb * 8 + c + 4) & 127;
    const size_t xoff = ((size_t)b * L_TOK + ho * 128 + wo) * C_DIM;
    const int j0 = q4 * 8;

    // ---- Phase A: load + LayerNorm1, stage to LDS as bf16 ----
    {
        const float* xp = x + xoff + q4 * 48;
        float f[48];
        float sum = 0.f, sq = 0.f;
        #pragma unroll
        for (int i = 0; i < 12; ++i) {
            float4 v = *(const float4*)(xp + i * 4);
            f[i*4+0]=v.x; f[i*4+1]=v.y; f[i*4+2]=v.z; f[i*4+3]=v.w;
            sum += v.x+v.y+v.z+v.w;
            sq  += v.x*v.x + v.y*v.y + v.z*v.z + v.w*v.w;
        }
        sum += __shfl_xor(sum, 1); sum += __shfl_xor(sum, 2);
        sq  += __shfl_xor(sq, 1);  sq  += __shfl_xor(sq, 2);
        const float mu = sum * (1.f / 192.f);
        const float rstd = rsqrtf(sq * (1.f / 192.f) - mu * mu + 1e-5f);
        u16* xrow = xw + n * 196 + q4 * 48;
        #pragma unroll
        for (int i = 0; i < 12; ++i) {
            float4 gv = *(const float4*)(g1v + q4 * 48 + i * 4);
            float4 bv = *(const float4*)(b1v + q4 * 48 + i * 4);
            float y0 = (f[i*4+0] - mu) * rstd * gv.x + bv.x;
            float y1 = (f[i*4+1] - mu) * rstd * gv.y + bv.y;
            float y2 = (f[i*4+2] - mu) * rstd * gv.z + bv.z;
            float y3 = (f[i*4+3] - mu) * rstd * gv.w + bv.w;
            u32 p0 = (u32)f2bf(y0) | (((u32)f2bf(y1)) << 16);
            u32 p1 = (u32)f2bf(y2) | (((u32)f2bf(y3)) << 16);
            *(int2*)(xrow + i * 4) = make_int2((int)p0, (int)p1);
        }
    }
    __syncthreads();

    const int regn = ((hb == 15) ? (r < 4 ? 1 : 2) : 0) * 3
                   + ((wb == 15) ? (c < 4 ? 1 : 2) : 0);

    float acc[48];
    #pragma unroll
    for (int i = 0; i < 48; ++i) acc[i] = 0.f;

    for (int head = 0; head < 6; ++head) {
        if (head) __syncthreads();   // prior iteration's LDS reads done

        // ---- Phase B: q,k,v for this head (K=192), f32 weights streamed ----
        {
            float aq[8], ak[8], av[8];
            #pragma unroll
            for (int j = 0; j < 8; ++j) { aq[j] = 0.f; ak[j] = 0.f; av[j] = 0.f; }
            const float* bq = qkvw + head * 32 + j0;
            const u16* xr = xw + n * 196;
            for (int kk = 0; kk < 192; ++kk) {
                float a = bf2f(xr[kk]);
                const float* wr = bq + kk * 576;
                float4 wq0 = *(const float4*)(wr);
                float4 wq1 = *(const float4*)(wr + 4);
                float4 wk0 = *(const float4*)(wr + 192);
                float4 wk1 = *(const float4*)(wr + 196);
                float4 wv0 = *(const float4*)(wr + 384);
                float4 wv1 = *(const float4*)(wr + 388);
                aq[0] = fmaf(a, wq0.x, aq[0]); aq[1] = fmaf(a, wq0.y, aq[1]);
                aq[2] = fmaf(a, wq0.z, aq[2]); aq[3] = fmaf(a, wq0.w, aq[3]);
                aq[4] = fmaf(a, wq1.x, aq[4]); aq[5] = fmaf(a, wq1.y, aq[5]);
                aq[6] = fmaf(a, wq1.z, aq[6]); aq[7] = fmaf(a, wq1.w, aq[7]);
                ak[0] = fmaf(a, wk0.x, ak[0]); ak[1] = fmaf(a, wk0.y, ak[1]);
                ak[2] = fmaf(a, wk0.z, ak[2]); ak[3] = fmaf(a, wk0.w, ak[3]);
                ak[4] = fmaf(a, wk1.x, ak[4]); ak[5] = fmaf(a, wk1.y, ak[5]);
                ak[6] = fmaf(a, wk1.z, ak[6]); ak[7] = fmaf(a, wk1.w, ak[7]);
                av[0] = fmaf(a, wv0.x, av[0]); av[1] = fmaf(a, wv0.y, av[1]);
                av[2] = fmaf(a, wv0.z, av[2]); av[3] = fmaf(a, wv0.w, av[3]);
                av[4] = fmaf(a, wv1.x, av[4]); av[5] = fmaf(a, wv1.y, av[5]);
                av[6] = fmaf(a, wv1.z, av[6]); av[7] = fmaf(a, wv1.w, av[7]);
            }
            const float scale = 0.17677669529663687f;   // 1/sqrt(32)
            #pragma unroll
            for (int j = 0; j < 8; ++j) {
                qs[n*33 + j0 + j] = (aq[j] + qkvb[head*32 + j0 + j]) * scale;
                ks[n*33 + j0 + j] =  ak[j] + qkvb[192 + head*32 + j0 + j];
                vs[n*33 + j0 + j] =  av[j] + qkvb[384 + head*32 + j0 + j];
            }
        }
        __syncthreads();

        // ---- Phase C: 16 scores (m = q4*16 .. +15) in registers ----
        const int m0 = q4 * 16;
        float sc_[16];
        for (int mi = 0; mi < 16; ++mi) {
            const int m = m0 + mi;
            float d = 0.f;
            #pragma unroll
            for (int kk = 0; kk < 32; ++kk) d = fmaf(qs[n*33 + kk], ks[m*33 + kk], d);
            const int rm = m >> 3, cm = m & 7;
            d += relb[((r - rm + 7) * 15 + (c - cm + 7)) * 6 + head];
            const int regm = ((hb == 15) ? (rm < 4 ? 1 : 2) : 0) * 3
                           + ((wb == 15) ? (cm < 4 ? 1 : 2) : 0);
            if (regm != regn) d -= 100.f;
            sc_[mi] = d;
        }
        // ---- Phase D: softmax across the row (quartet shfl) ----
        {
            float mx = -1e30f;
            #pragma unroll
            for (int mi = 0; mi < 16; ++mi) mx = fmaxf(mx, sc_[mi]);
            mx = fmaxf(mx, __shfl_xor(mx, 1)); mx = fmaxf(mx, __shfl_xor(mx, 2));
            float s = 0.f;
            #pragma unroll
            for (int mi = 0; mi < 16; ++mi) { sc_[mi] = __expf(sc_[mi] - mx); s += sc_[mi]; }
            s += __shfl_xor(s, 1); s += __shfl_xor(s, 2);
            const float inv = 1.f / s;
            #pragma unroll
            for (int mi = 0; mi < 16; ++mi) sc_[mi] *= inv;
        }
        // ---- Phase E: partial P@V over own m-chunk, butterfly to full row ----
        float o[32];
        #pragma unroll
        for (int j = 0; j < 32; ++j) o[j] = 0.f;
        for (int mi = 0; mi < 16; ++mi) {
            const float p = sc_[mi];
            const float* vr = vs + (m0 + mi) * 33;
            #pragma unroll
            for (int j = 0; j < 32; ++j) o[j] = fmaf(p, vr[j], o[j]);
        }
        #pragma unroll
        for (int j = 0; j < 32; ++j) {
            o[j] += __shfl_xor(o[j], 1);
            o[j] += __shfl_xor(o[j], 2);
        }
        // ---- Phase P: proj partial  acc[c] += o[k] * projw[head*32+k][q4*48+c] ----
        {
            const float* pw = projw + (size_t)(head * 32) * C_DIM + q4 * 48;
            for (int k = 0; k < 32; ++k) {
                const float ok = o[k];
                const float* wr = pw + k * C_DIM;
                #pragma unroll
                for (int i4 = 0; i4 < 12; ++i4) {
                    float4 w = *(const float4*)(wr + i4 * 4);
                    acc[i4*4+0] = fmaf(ok, w.x, acc[i4*4+0]);
                    acc[i4*4+1] = fmaf(ok, w.y, acc[i4*4+1]);
                    acc[i4*4+2] = fmaf(ok, w.z, acc[i4*4+2]);
                    acc[i4*4+3] = fmaf(ok, w.w, acc[i4*4+3]);
                }
            }
        }
    }

    // ---- Phase F: + proj bias + residual, write x1 (f32, token order) ----
    {
        const float* xp = x + xoff + q4 * 48;
        float* op = x1 + xoff + q4 * 48;
        #pragma unroll
        for (int i = 0; i < 12; ++i) {
            float4 xr = *(const float4*)(xp + i * 4);
            float4 pb = *(const float4*)(projb + q4 * 48 + i * 4);
            float4 ov;
            ov.x = acc[i*4+0] + pb.x + xr.x;
            ov.y = acc[i*4+1] + pb.y + xr.y;
            ov.z = acc[i*4+2] + pb.z + xr.z;
            ov.w = acc[i*4+3] + pb.w + xr.w;
            *(float4*)(op + i * 4) = ov;
        }
    }
}

// ---------------------------------------------------------------------------
// Kernel 2: fused LN2 + fc1 + exact GELU + fc2 + residual, IN-PLACE on d_out
// (x1 f32 in, out f32 same buffer).  Hidden chunked by 48 through LDS.
// grid 2048, block 256. LDS 56064 B -> 2 blocks/CU.
// NOTE: x1/out intentionally NOT __restrict__ (same buffer).
// ---------------------------------------------------------------------------
__global__ __launch_bounds__(256) void k_mlp(
    const float* x1, const float* __restrict__ g2v, const float* __restrict__ b2v,
    const float* __restrict__ fc1w, const float* __restrict__ fc1b,
    const float* __restrict__ fc2w, const float* __restrict__ fc2b,
    float* out)
{
    __shared__ __align__(16) char smem[25088 + 18432 + 12544];
    u16*  Axn = (u16*)smem;                     // [64][196] LN2'd tokens (bf16-compressed)
    u16*  Wc  = (u16*)(smem + 25088);           // [192][48] fc1 chunk / [48][192] fc2 chunk (bf16)
    float* Hs = (float*)(smem + 25088 + 18432); // [64][49] GELU'd hidden chunk

    const int blk = blockIdx.x;
    const int t = threadIdx.x;
    const size_t row0 = (size_t)blk * 64;

    {   // LN2 staging (reads x1; all reads complete before first __syncthreads)
        const int n = t >> 2, q4 = t & 3;
        const float* xp = x1 + (row0 + n) * C_DIM + q4 * 48;
        float f[48];
        float sum = 0.f, sq = 0.f;
        #pragma unroll
        for (int i = 0; i < 12; ++i) {
            float4 v = *(const float4*)(xp + i * 4);
            f[i*4+0]=v.x; f[i*4+1]=v.y; f[i*4+2]=v.z; f[i*4+3]=v.w;
            sum += v.x+v.y+v.z+v.w;
            sq  += v.x*v.x + v.y*v.y + v.z*v.z + v.w*v.w;
        }
        sum += __shfl_xor(sum,1); sum += __shfl_xor(sum,2);
        sq  += __shfl_xor(sq,1);  sq  += __shfl_xor(sq,2);
        const float mu = sum * (1.f/192.f);
        const float rstd = rsqrtf(sq * (1.f/192.f) - mu*mu + 1e-5f);
        u16* xrow = Axn + n * 196 + q4 * 48;
        #pragma unroll
        for (int i = 0; i < 12; ++i) {
            float4 gv = *(const float4*)(g2v + q4*48 + i*4);
            float4 bv = *(const float4*)(b2v + q4*48 + i*4);
            float y0 = (f[i*4+0] - mu) * rstd * gv.x + bv.x;
            float y1 = (f[i*4+1] - mu) * rstd * gv.y + bv.y;
            float y2 = (f[i*4+2] - mu) * rstd * gv.z + bv.z;
            float y3 = (f[i*4+3] - mu) * rstd * gv.w + bv.w;
            u32 p0 = (u32)f2bf(y0) | (((u32)f2bf(y1)) << 16);
            u32 p1 = (u32)f2bf(y2) | (((u32)f2bf(y3)) << 16);
            *(int2*)(xrow + i*4) = make_int2((int)p0, (int)p1);
        }
    }

    const int th = t >> 4, tw = t & 15;
    float acc[48];
    #pragma unroll
    for (int i = 0; i < 48; ++i) acc[i] = 0.f;

    for (int hc = 0; hc < 16; ++hc) {
        __syncthreads();
        #pragma unroll
        for (int i = 0; i < 9; ++i) {         // stage fc1[:, hc*48 : +48] -> bf16
            const int idx = t + i * 256;
            const int row = idx / 12, c4 = idx % 12;
            float4 d = *(const float4*)(fc1w + (size_t)row * HID_DIM + hc * 48 + c4 * 4);
            u32 p0 = (u32)f2bf(d.x) | (((u32)f2bf(d.y)) << 16);
            u32 p1 = (u32)f2bf(d.z) | (((u32)f2bf(d.w)) << 16);
            *(int2*)(Wc + row * 48 + c4 * 4) = make_int2((int)p0, (int)p1);
        }
        __syncthreads();
        float ha[12];
        #pragma unroll
        for (int i = 0; i < 12; ++i) ha[i] = 0.f;
        for (int kk = 0; kk < 192; ++kk) {    // H = Axn @ W1c
            float a[4];
            #pragma unroll
            for (int i = 0; i < 4; ++i) a[i] = bf2f(Axn[(th*4+i)*196 + kk]);
            float w[3];
            #pragma unroll
            for (int j = 0; j < 3; ++j) w[j] = bf2f(Wc[kk*48 + tw*3 + j]);
            #pragma unroll
            for (int i = 0; i < 4; ++i)
                #pragma unroll
                for (int j = 0; j < 3; ++j)
                    ha[i*3+j] = fmaf(a[i], w[j], ha[i*3+j]);
        }
        #pragma unroll
        for (int j = 0; j < 3; ++j) {
            const float bb = fc1b[hc*48 + tw*3 + j];
            #pragma unroll
            for (int i = 0; i < 4; ++i) {
                float h = ha[i*3+j] + bb;
                float g = 0.5f * h * (1.f + erff(h * 0.70710678118654752f)); // exact GELU
                Hs[(th*4+i)*49 + tw*3 + j] = g;
            }
        }
        __syncthreads();
        #pragma unroll
        for (int i = 0; i < 9; ++i) {         // stage fc2[hc*48 : +48, :] -> bf16
            const int idx = t + i * 256;
            const int row = idx / 48, c4 = idx % 48;
            float4 d = *(const float4*)(fc2w + (size_t)(hc*48 + row) * C_DIM + c4 * 4);
            u32 p0 = (u32)f2bf(d.x) | (((u32)f2bf(d.y)) << 16);
            u32 p1 = (u32)f2bf(d.z) | (((u32)f2bf(d.w)) << 16);
            *(int2*)(Wc + row * C_DIM + c4 * 4) = make_int2((int)p0, (int)p1);
        }
        __syncthreads();
        for (int kk = 0; kk < 48; ++kk) {     // acc += H @ W2c
            float a[4];
            #pragma unroll
            for (int i = 0; i < 4; ++i) a[i] = Hs[(th*4+i)*49 + kk];
            const u16* br = Wc + kk * C_DIM + tw * 12;
            float bv[12];
            #pragma unroll
            for (int j = 0; j < 12; ++j) bv[j] = bf2f(br[j]);
            #pragma unroll
            for (int i = 0; i < 4; ++i)
                #pragma unroll
                for (int j = 0; j < 12; ++j)
                    acc[i*12+j] = fmaf(a[i], bv[j], acc[i*12+j]);
        }
    }

    float fb[12];
    #pragma unroll
    for (int j = 0; j < 12; ++j) fb[j] = fc2b[tw*12 + j];
    #pragma unroll
    for (int i = 0; i < 4; ++i) {
        const size_t base = (row0 + th*4 + i) * C_DIM + tw * 12;
        #pragma unroll
        for (int j2 = 0; j2 < 3; ++j2) {       // residual: thread-private cells only
            float4 rv = *(const float4*)(x1 + base + j2*4);
            float4 ov;
            ov.x = acc[i*12 + j2*4 + 0] + fb[j2*4+0] + rv.x;
            ov.y = acc[i*12 + j2*4 + 1] + fb[j2*4+1] + rv.y;
            ov.z = acc[i*12 + j2*4 + 2] + fb[j2*4+2] + rv.z;
            ov.w = acc[i*12 + j2*4 + 3] + fb[j2*4+3] + rv.w;
            *(float4*)(out + base + j2*4) = ov;
        }
    }
}

extern "C" void kernel_launch(void* const* d_in, const int* in_sizes, int n_in,
                              void* d_out, int out_size, void* d_ws, size_t ws_size,
                              hipStream_t stream) {
    const float* x     = (const float*)d_in[0];
    // d_in[1]=h, d_in[2]=w (ints, fixed 128 -> hardcoded)
    const float* g1v   = (const float*)d_in[3];
    const float* b1v   = (const float*)d_in[4];
    const float* qkvw  = (const float*)d_in[5];
    const float* qkvb  = (const float*)d_in[6];
    const float* projw = (const float*)d_in[7];
    const float* projb = (const float*)d_in[8];
    const float* relb  = (const float*)d_in[9];
    const float* g2v   = (const float*)d_in[10];
    const float* b2v   = (const float*)d_in[11];
    const float* fc1w  = (const float*)d_in[12];
    const float* fc1b  = (const float*)d_in[13];
    const float* fc2w  = (const float*)d_in[14];
    const float* fc2b  = (const float*)d_in[15];

    float* x1 = (float*)d_out;   // residual stream after attention, f32, token order
                                 // (d_ws is NOT used at all)

    hipLaunchKernelGGL(k_attnproj, dim3(2048), dim3(256), 0, stream,
                       x, g1v, b1v, qkvw, qkvb, relb, projw, projb, x1);
    hipLaunchKernelGGL(k_mlp, dim3(2048), dim3(256), 0, stream,
                       x1, g2v, b2v, fc1w, fc1b, fc2w, fc2b, x1);  // in-place
}

// Round 4
// 2315.842 us; speedup vs baseline: 3.7058x; 3.7058x over previous
//
#include <hip/hip_runtime.h>

typedef unsigned short u16;
typedef unsigned int   u32;
typedef __attribute__((ext_vector_type(8))) short bf16x8;
typedef __attribute__((ext_vector_type(4))) float f32x4;

#define L_TOK   16384
#define C_DIM   192
#define HID_DIM 768

union FragU { int4 i4; bf16x8 h8; };

#define MFMA_B16(a,b,c) __builtin_amdgcn_mfma_f32_16x16x32_bf16(a,b,c,0,0,0)
// row permutation for q/k/v LDS tiles: breaks the "4 rows, same bank-window"
// conflict pattern of quartet-chunked row loads (stride 40 u16 = 20 words).
#define PROW(m) ((((m)&3)<<4) | ((m)>>2))

__device__ __forceinline__ float bf2f(u16 u) {
    u32 t = ((u32)u) << 16; float f; __builtin_memcpy(&f, &t, 4); return f;
}
__device__ __forceinline__ u16 f2bf(float f) {
    u32 t; __builtin_memcpy(&t, &f, 4);
    t += 0x7FFFu + ((t >> 16) & 1u);
    return (u16)(t >> 16);
}
__device__ __forceinline__ void bf2x2(u32 w, float& lo, float& hi) {
    u32 a = w << 16, b = w & 0xFFFF0000u;
    __builtin_memcpy(&lo, &a, 4); __builtin_memcpy(&hi, &b, 4);
}
__device__ __forceinline__ void unpack32(const u16* p, float* f) {
    const int4* q = (const int4*)p;
    int4 v0 = q[0], v1 = q[1], v2 = q[2], v3 = q[3];
    bf2x2((u32)v0.x, f[0], f[1]);   bf2x2((u32)v0.y, f[2], f[3]);
    bf2x2((u32)v0.z, f[4], f[5]);   bf2x2((u32)v0.w, f[6], f[7]);
    bf2x2((u32)v1.x, f[8], f[9]);   bf2x2((u32)v1.y, f[10], f[11]);
    bf2x2((u32)v1.z, f[12], f[13]); bf2x2((u32)v1.w, f[14], f[15]);
    bf2x2((u32)v2.x, f[16], f[17]); bf2x2((u32)v2.y, f[18], f[19]);
    bf2x2((u32)v2.z, f[20], f[21]); bf2x2((u32)v2.w, f[22], f[23]);
    bf2x2((u32)v3.x, f[24], f[25]); bf2x2((u32)v3.y, f[26], f[27]);
    bf2x2((u32)v3.z, f[28], f[29]); bf2x2((u32)v3.w, f[30], f[31]);
}

// ---------------------------------------------------------------------------
// Kernel 1: per-window fused LN1 + MFMA qkv + biased/masked softmax + P@V +
// proj(VALU) + residual -> x1 (f32, token order, in d_out).
// grid 2048, block 256 (4 waves; wave w owns tokens w*16..+15 = M-tile w).
// LDS 53760 B -> 3 blocks/CU.
// ---------------------------------------------------------------------------
__global__ __launch_bounds__(256) void k_attnproj(
    const float* __restrict__ x, const float* __restrict__ g1v, const float* __restrict__ b1v,
    const float* __restrict__ qkvw, const float* __restrict__ qkvb,
    const float* __restrict__ relb, const float* __restrict__ projw, const float* __restrict__ projb,
    float* __restrict__ x1)
{
    __shared__ __align__(16) u16 xw[64 * 192];     // LN1'd tokens, bf16, stride 192
    __shared__ __align__(16) u16 wTh[96 * 72];     // W^T chunk [col 0..95][k 0..63], stride 72
    __shared__ __align__(16) u16 qsb[64 * 40];     // PROW-permuted rows, stride 40
    __shared__ __align__(16) u16 ksb[64 * 40];
    __shared__ __align__(16) u16 vsb[64 * 40];

    const int wi = blockIdx.x;
    const int b  = wi >> 8;
    const int hb = (wi >> 4) & 15;
    const int wb = wi & 15;
    const int t  = threadIdx.x;
    const int n  = t >> 2;        // token in window
    const int q4 = t & 3;         // quartet lane
    const int r  = n >> 3, c = n & 7;
    const int ho = (hb * 8 + r + 4) & 127;    // undo roll(-4,-4)
    const int wo = (wb * 8 + c + 4) & 127;
    const size_t xoff = ((size_t)b * L_TOK + ho * 128 + wo) * C_DIM;
    const int lane = t & 63, w = t >> 6;
    const int l15 = lane & 15, quad = lane >> 4;

    // ---- Phase A: load + LayerNorm1, stage to LDS as bf16 ----
    {
        const float* xp = x + xoff + q4 * 48;
        float f[48];
        float sum = 0.f, sq = 0.f;
        #pragma unroll
        for (int i = 0; i < 12; ++i) {
            float4 v = *(const float4*)(xp + i * 4);
            f[i*4+0]=v.x; f[i*4+1]=v.y; f[i*4+2]=v.z; f[i*4+3]=v.w;
            sum += v.x+v.y+v.z+v.w;
            sq  += v.x*v.x + v.y*v.y + v.z*v.z + v.w*v.w;
        }
        sum += __shfl_xor(sum, 1); sum += __shfl_xor(sum, 2);
        sq  += __shfl_xor(sq, 1);  sq  += __shfl_xor(sq, 2);
        const float mu = sum * (1.f / 192.f);
        const float rstd = rsqrtf(sq * (1.f / 192.f) - mu * mu + 1e-5f);
        u16* xrow = xw + n * 192 + q4 * 48;
        #pragma unroll
        for (int i = 0; i < 6; ++i) {
            u32 pk[4];
            #pragma unroll
            for (int j = 0; j < 4; ++j) {
                float g0 = g1v[q4*48 + i*8 + j*2],     b0 = b1v[q4*48 + i*8 + j*2];
                float g1 = g1v[q4*48 + i*8 + j*2 + 1], b1 = b1v[q4*48 + i*8 + j*2 + 1];
                float y0 = (f[i*8+j*2]   - mu) * rstd * g0 + b0;
                float y1 = (f[i*8+j*2+1] - mu) * rstd * g1 + b1;
                pk[j] = (u32)f2bf(y0) | (((u32)f2bf(y1)) << 16);
            }
            *(int4*)(xrow + i * 8) = make_int4((int)pk[0], (int)pk[1], (int)pk[2], (int)pk[3]);
        }
    }
    __syncthreads();

    // preload A-fragments (tokens of this wave's M-tile), reused for all heads
    FragU afrag[6];
    #pragma unroll
    for (int kk = 0; kk < 6; ++kk)
        afrag[kk].i4 = *(const int4*)(xw + (w*16 + l15) * 192 + kk*32 + quad*8);

    const int regn = ((hb == 15) ? (r < 4 ? 1 : 2) : 0) * 3
                   + ((wb == 15) ? (c < 4 ? 1 : 2) : 0);

    float acc[48];
    #pragma unroll
    for (int i = 0; i < 48; ++i) acc[i] = 0.f;

    for (int head = 0; head < 6; ++head) {
        // ---- Phase B: qkv via MFMA (N=96: q|k|v 32 each), K chunked by 64 ----
        f32x4 accq[6];
        #pragma unroll
        for (int nt = 0; nt < 6; ++nt) accq[nt] = (f32x4){0.f, 0.f, 0.f, 0.f};

        for (int kc = 0; kc < 3; ++kc) {
            __syncthreads();   // wTh reuse safe; also orders prev head's qkv reads
            if (t < 192) {     // stage W^T chunk: col cc, k-half kh
                const int cc = t % 96, kh = t / 96;
                const int grp = cc >> 5, dim = cc & 31;
                const float* gp = qkvw + (size_t)(kc*64 + kh*32) * 576 + grp*192 + head*32 + dim;
                u16* dst = wTh + cc*72 + kh*32;
                #pragma unroll
                for (int g = 0; g < 4; ++g) {
                    u32 pk[4];
                    #pragma unroll
                    for (int j2 = 0; j2 < 4; ++j2) {
                        float v0 = gp[(size_t)(g*8 + j2*2    ) * 576];
                        float v1 = gp[(size_t)(g*8 + j2*2 + 1) * 576];
                        pk[j2] = (u32)f2bf(v0) | (((u32)f2bf(v1)) << 16);
                    }
                    *(int4*)(dst + g*8) = make_int4((int)pk[0], (int)pk[1], (int)pk[2], (int)pk[3]);
                }
            }
            __syncthreads();
            #pragma unroll
            for (int s = 0; s < 2; ++s) {
                #pragma unroll
                for (int nt = 0; nt < 6; ++nt) {
                    FragU bf_;
                    bf_.i4 = *(const int4*)(wTh + (nt*16 + l15)*72 + s*32 + quad*8);
                    accq[nt] = MFMA_B16(afrag[kc*2 + s].h8, bf_.h8, accq[nt]);
                }
            }
        }
        // write q/k/v (bf16, PROW rows); D: tok = w*16+quad*4+rg, col = nt*16+l15
        #pragma unroll
        for (int nt = 0; nt < 6; ++nt) {
            const int cc = nt*16 + l15;
            const int grp = cc >> 5, dim = cc & 31;
            const float bias = qkvb[grp*192 + head*32 + dim];
            u16* dst = (grp == 0) ? qsb : (grp == 1 ? ksb : vsb);
            #pragma unroll
            for (int rg = 0; rg < 4; ++rg) {
                const int tok = w*16 + quad*4 + rg;
                float v = accq[nt][rg] + bias;
                if (grp == 0) v *= 0.17677669529663687f;   // 1/sqrt(32)
                dst[PROW(tok)*40 + dim] = f2bf(v);
            }
        }
        __syncthreads();

        // ---- Phase C: 16 scores (m = q4*16..+15) via vector row loads ----
        const int m0 = q4 * 16;
        float qreg[32];
        unpack32(qsb + PROW(n)*40, qreg);
        float sc_[16];
        for (int mi = 0; mi < 16; ++mi) {
            const int m = m0 + mi;
            float kreg[32];
            unpack32(ksb + PROW(m)*40, kreg);
            float d = 0.f;
            #pragma unroll
            for (int kk = 0; kk < 32; ++kk) d = fmaf(qreg[kk], kreg[kk], d);
            const int rm = m >> 3, cm = m & 7;
            d += relb[((r - rm + 7) * 15 + (c - cm + 7)) * 6 + head];
            const int regm = ((hb == 15) ? (rm < 4 ? 1 : 2) : 0) * 3
                           + ((wb == 15) ? (cm < 4 ? 1 : 2) : 0);
            if (regm != regn) d -= 100.f;
            sc_[mi] = d;
        }
        // ---- Phase D: softmax across the row (quartet shfl) ----
        {
            float mx = -1e30f;
            #pragma unroll
            for (int mi = 0; mi < 16; ++mi) mx = fmaxf(mx, sc_[mi]);
            mx = fmaxf(mx, __shfl_xor(mx, 1)); mx = fmaxf(mx, __shfl_xor(mx, 2));
            float s = 0.f;
            #pragma unroll
            for (int mi = 0; mi < 16; ++mi) { sc_[mi] = __expf(sc_[mi] - mx); s += sc_[mi]; }
            s += __shfl_xor(s, 1); s += __shfl_xor(s, 2);
            const float inv = 1.f / s;
            #pragma unroll
            for (int mi = 0; mi < 16; ++mi) sc_[mi] *= inv;
        }
        // ---- Phase E: partial P@V over own m-chunk, butterfly to full row ----
        float o[32];
        #pragma unroll
        for (int j = 0; j < 32; ++j) o[j] = 0.f;
        for (int mi = 0; mi < 16; ++mi) {
            float vreg[32];
            unpack32(vsb + PROW(m0 + mi)*40, vreg);
            const float p = sc_[mi];
            #pragma unroll
            for (int j = 0; j < 32; ++j) o[j] = fmaf(p, vreg[j], o[j]);
        }
        #pragma unroll
        for (int j = 0; j < 32; ++j) {
            o[j] += __shfl_xor(o[j], 1);
            o[j] += __shfl_xor(o[j], 2);
        }
        // ---- Phase P: proj partial  acc[cc] += o[k] * projw[head*32+k][q4*48+cc] ----
        {
            const float* pw = projw + (size_t)(head * 32) * C_DIM + q4 * 48;
            for (int k = 0; k < 32; ++k) {
                const float ok = o[k];
                const float* wr = pw + k * C_DIM;
                #pragma unroll
                for (int i4 = 0; i4 < 12; ++i4) {
                    float4 wv = *(const float4*)(wr + i4 * 4);
                    acc[i4*4+0] = fmaf(ok, wv.x, acc[i4*4+0]);
                    acc[i4*4+1] = fmaf(ok, wv.y, acc[i4*4+1]);
                    acc[i4*4+2] = fmaf(ok, wv.z, acc[i4*4+2]);
                    acc[i4*4+3] = fmaf(ok, wv.w, acc[i4*4+3]);
                }
            }
        }
    }

    // ---- Phase F: + proj bias + residual, write x1 (f32, token order) ----
    {
        const float* xp = x + xoff + q4 * 48;
        float* op = x1 + xoff + q4 * 48;
        #pragma unroll
        for (int i = 0; i < 12; ++i) {
            float4 xr = *(const float4*)(xp + i * 4);
            float4 pb = *(const float4*)(projb + q4 * 48 + i * 4);
            float4 ov;
            ov.x = acc[i*4+0] + pb.x + xr.x;
            ov.y = acc[i*4+1] + pb.y + xr.y;
            ov.z = acc[i*4+2] + pb.z + xr.z;
            ov.w = acc[i*4+3] + pb.w + xr.w;
            *(float4*)(op + i * 4) = ov;
        }
    }
}

// ---------------------------------------------------------------------------
// Kernel 2: fused LN2 + MFMA fc1 + GELU + MFMA fc2 + residual, in-place on
// d_out. Hidden chunked by 96 (one LDS h-tile); weights staged transposed.
// grid 2048, block 256. LDS 53248 B -> 3 blocks/CU.
// ---------------------------------------------------------------------------
__global__ __launch_bounds__(256) void k_mlp(
    const float* x1, const float* __restrict__ g2v, const float* __restrict__ b2v,
    const float* __restrict__ fc1w, const float* __restrict__ fc1b,
    const float* __restrict__ fc2w, const float* __restrict__ fc2b,
    float* out)
{
    __shared__ __align__(16) u16 xn[64 * 192];    // LN2'd tokens bf16, stride 192
    __shared__ __align__(16) u16 wT[192 * 40];    // shared: w1T[96][72] / w2T[192][40]
    __shared__ __align__(16) u16 hbuf[64 * 104];  // GELU'd hidden chunk, stride 104

    const int blk = blockIdx.x;
    const int t = threadIdx.x;
    const size_t row0 = (size_t)blk * 64;
    const int lane = t & 63, w = t >> 6;
    const int l15 = lane & 15, quad = lane >> 4;

    {   // LN2 staging
        const int nn = t >> 2, q4 = t & 3;
        const float* xp = x1 + (row0 + nn) * C_DIM + q4 * 48;
        float f[48];
        float sum = 0.f, sq = 0.f;
        #pragma unroll
        for (int i = 0; i < 12; ++i) {
            float4 v = *(const float4*)(xp + i * 4);
            f[i*4+0]=v.x; f[i*4+1]=v.y; f[i*4+2]=v.z; f[i*4+3]=v.w;
            sum += v.x+v.y+v.z+v.w;
            sq  += v.x*v.x + v.y*v.y + v.z*v.z + v.w*v.w;
        }
        sum += __shfl_xor(sum,1); sum += __shfl_xor(sum,2);
        sq  += __shfl_xor(sq,1);  sq  += __shfl_xor(sq,2);
        const float mu = sum * (1.f/192.f);
        const float rstd = rsqrtf(sq * (1.f/192.f) - mu*mu + 1e-5f);
        u16* xrow = xn + nn * 192 + q4 * 48;
        #pragma unroll
        for (int i = 0; i < 6; ++i) {
            u32 pk[4];
            #pragma unroll
            for (int j = 0; j < 4; ++j) {
                float g0 = g2v[q4*48 + i*8 + j*2],     b0 = b2v[q4*48 + i*8 + j*2];
                float g1 = g2v[q4*48 + i*8 + j*2 + 1], b1 = b2v[q4*48 + i*8 + j*2 + 1];
                float y0 = (f[i*8+j*2]   - mu) * rstd * g0 + b0;
                float y1 = (f[i*8+j*2+1] - mu) * rstd * g1 + b1;
                pk[j] = (u32)f2bf(y0) | (((u32)f2bf(y1)) << 16);
            }
            *(int4*)(xrow + i*8) = make_int4((int)pk[0], (int)pk[1], (int)pk[2], (int)pk[3]);
        }
    }
    __syncthreads();

    FragU afrag[6];
    #pragma unroll
    for (int kk = 0; kk < 6; ++kk)
        afrag[kk].i4 = *(const int4*)(xn + (w*16 + l15) * 192 + kk*32 + quad*8);

    f32x4 acc2[12];
    #pragma unroll
    for (int nt = 0; nt < 12; ++nt) acc2[nt] = (f32x4){0.f, 0.f, 0.f, 0.f};

    for (int hc = 0; hc < 8; ++hc) {
        // ---- fc1 for hidden cols [hc*96, +96) ----
        f32x4 acc1[6];
        #pragma unroll
        for (int nt = 0; nt < 6; ++nt) acc1[nt] = (f32x4){0.f, 0.f, 0.f, 0.f};

        for (int kc = 0; kc < 3; ++kc) {
            __syncthreads();
            if (t < 192) {
                const int cc = t % 96, kh = t / 96;
                const float* gp = fc1w + (size_t)(kc*64 + kh*32) * HID_DIM + hc*96 + cc;
                u16* dst = wT + cc*72 + kh*32;
                #pragma unroll
                for (int g = 0; g < 4; ++g) {
                    u32 pk[4];
                    #pragma unroll
                    for (int j2 = 0; j2 < 4; ++j2) {
                        float v0 = gp[(size_t)(g*8 + j2*2    ) * HID_DIM];
                        float v1 = gp[(size_t)(g*8 + j2*2 + 1) * HID_DIM];
                        pk[j2] = (u32)f2bf(v0) | (((u32)f2bf(v1)) << 16);
                    }
                    *(int4*)(dst + g*8) = make_int4((int)pk[0], (int)pk[1], (int)pk[2], (int)pk[3]);
                }
            }
            __syncthreads();
            #pragma unroll
            for (int s = 0; s < 2; ++s) {
                #pragma unroll
                for (int nt = 0; nt < 6; ++nt) {
                    FragU bf_;
                    bf_.i4 = *(const int4*)(wT + (nt*16 + l15)*72 + s*32 + quad*8);
                    acc1[nt] = MFMA_B16(afrag[kc*2 + s].h8, bf_.h8, acc1[nt]);
                }
            }
        }
        // ---- bias + exact GELU -> hbuf (bf16) ----
        #pragma unroll
        for (int nt = 0; nt < 6; ++nt) {
            const float bb = fc1b[hc*96 + nt*16 + l15];
            #pragma unroll
            for (int rg = 0; rg < 4; ++rg) {
                float h = acc1[nt][rg] + bb;
                float g = 0.5f * h * (1.f + erff(h * 0.70710678118654752f));
                hbuf[(w*16 + quad*4 + rg) * 104 + nt*16 + l15] = f2bf(g);
            }
        }
        // ---- fc2 partial over this hidden chunk (3 sub-chunks of 32) ----
        for (int sc = 0; sc < 3; ++sc) {
            __syncthreads();   // hbuf visible; wT reuse safe
            if (t < 192) {
                const float* gp = fc2w + (size_t)(hc*96 + sc*32) * C_DIM + t;
                u16* dst = wT + t*40;
                #pragma unroll
                for (int g = 0; g < 4; ++g) {
                    u32 pk[4];
                    #pragma unroll
                    for (int j2 = 0; j2 < 4; ++j2) {
                        float v0 = gp[(size_t)(g*8 + j2*2    ) * C_DIM];
                        float v1 = gp[(size_t)(g*8 + j2*2 + 1) * C_DIM];
                        pk[j2] = (u32)f2bf(v0) | (((u32)f2bf(v1)) << 16);
                    }
                    *(int4*)(dst + g*8) = make_int4((int)pk[0], (int)pk[1], (int)pk[2], (int)pk[3]);
                }
            }
            __syncthreads();
            FragU ha;
            ha.i4 = *(const int4*)(hbuf + (w*16 + l15) * 104 + sc*32 + quad*8);
            #pragma unroll
            for (int nt = 0; nt < 12; ++nt) {
                FragU bf_;
                bf_.i4 = *(const int4*)(wT + (nt*16 + l15)*40 + quad*8);
                acc2[nt] = MFMA_B16(ha.h8, bf_.h8, acc2[nt]);
            }
        }
    }

    // ---- epilogue: + fc2 bias + residual (in-place safe: 1 owner per cell) ----
    #pragma unroll
    for (int nt = 0; nt < 12; ++nt) {
        const int col = nt*16 + l15;
        const float bb = fc2b[col];
        #pragma unroll
        for (int rg = 0; rg < 4; ++rg) {
            const size_t idx = (row0 + w*16 + quad*4 + rg) * C_DIM + col;
            out[idx] = acc2[nt][rg] + bb + x1[idx];
        }
    }
}

extern "C" void kernel_launch(void* const* d_in, const int* in_sizes, int n_in,
                              void* d_out, int out_size, void* d_ws, size_t ws_size,
                              hipStream_t stream) {
    const float* x     = (const float*)d_in[0];
    // d_in[1]=h, d_in[2]=w (ints, fixed 128 -> hardcoded)
    const float* g1v   = (const float*)d_in[3];
    const float* b1v   = (const float*)d_in[4];
    const float* qkvw  = (const float*)d_in[5];
    const float* qkvb  = (const float*)d_in[6];
    const float* projw = (const float*)d_in[7];
    const float* projb = (const float*)d_in[8];
    const float* relb  = (const float*)d_in[9];
    const float* g2v   = (const float*)d_in[10];
    const float* b2v   = (const float*)d_in[11];
    const float* fc1w  = (const float*)d_in[12];
    const float* fc1b  = (const float*)d_in[13];
    const float* fc2w  = (const float*)d_in[14];
    const float* fc2b  = (const float*)d_in[15];

    float* x1 = (float*)d_out;   // residual stream after attention (f32, token order)

    hipLaunchKernelGGL(k_attnproj, dim3(2048), dim3(256), 0, stream,
                       x, g1v, b1v, qkvw, qkvb, relb, projw, projb, x1);
    hipLaunchKernelGGL(k_mlp, dim3(2048), dim3(256), 0, stream,
                       x1, g2v, b2v, fc1w, fc1b, fc2w, fc2b, x1);  // in-place
}